// Round 1
// baseline (95.384 us; speedup 1.0000x reference)
//
#include <hip/hip_runtime.h>
#include <hip/hip_fp16.h>

// Problem constants (from reference)
constexpr int B  = 32, C = 256, H = 112, W = 112;
constexpr int OH = 56, OW = 56;
constexpr int NOUT = B * C * OH * OW;        // 25,690,112 outputs (fits int32)
constexpr int OW4  = OW / 4;                 // 14 thread-columns per output row

// fp16 quantize: float -> half (RNE, HW cvt) -> float. Matches reference
// float_quantize(EXP=5, MAN=10) for all values reachable here (|x| << 65504).
__device__ __forceinline__ float q16(float v) {
    return __half2float(__float2half(v));
}

__device__ __forceinline__ float pool4(float x00, float x01, float x10, float x11) {
    // Exact reference order: (m,n) = (0,0),(0,1),(1,0),(1,1), quantize each step.
    float acc = q16(x00);
    acc = q16(acc + x01);
    acc = q16(acc + x10);
    acc = q16(acc + x11);
    return q16(acc * 0.25f);   // /4 is exact in fp32; final quantize
}

__global__ __launch_bounds__(256)
void qavgpool2d_kernel(const float* __restrict__ x, float* __restrict__ y) {
    int t = blockIdx.x * blockDim.x + threadIdx.x;   // one thread = 4 outputs along W
    // total threads = NOUT/4 = 6,422,528; grid sized exactly, no bounds check needed
    int ow4 = t % OW4;
    int tmp = t / OW4;
    int oh  = tmp % OH;
    int bc  = tmp / OH;                               // fused (b, c) index, < 8192

    int ow0 = ow4 * 4;                                // output col start (mult of 4)
    int ih0 = oh * 2;                                 // input row

    const float* row0 = x + (size_t)bc * (H * W) + ih0 * W + ow0 * 2;
    const float* row1 = row0 + W;

    // 8 consecutive input floats per row: two aligned float4 loads each.
    float4 a0 = *reinterpret_cast<const float4*>(row0);
    float4 a1 = *reinterpret_cast<const float4*>(row0 + 4);
    float4 b0 = *reinterpret_cast<const float4*>(row1);
    float4 b1 = *reinterpret_cast<const float4*>(row1 + 4);

    float4 o;
    o.x = pool4(a0.x, a0.y, b0.x, b0.y);
    o.y = pool4(a0.z, a0.w, b0.z, b0.w);
    o.z = pool4(a1.x, a1.y, b1.x, b1.y);
    o.w = pool4(a1.z, a1.w, b1.z, b1.w);

    float* yp = y + (size_t)bc * (OH * OW) + oh * OW + ow0;
    *reinterpret_cast<float4*>(yp) = o;
}

extern "C" void kernel_launch(void* const* d_in, const int* in_sizes, int n_in,
                              void* d_out, int out_size, void* d_ws, size_t ws_size,
                              hipStream_t stream) {
    const float* x = (const float*)d_in[0];
    float*       y = (float*)d_out;

    constexpr int threads = 256;
    constexpr int nthreads_total = NOUT / 4;          // 6,422,528
    constexpr int blocks = nthreads_total / threads;  // 25,088 exactly

    qavgpool2d_kernel<<<blocks, threads, 0, stream>>>(x, y);
}

// Round 3
// 87.708 us; speedup vs baseline: 1.0875x; 1.0875x over previous
//
#include <hip/hip_runtime.h>
#include <hip/hip_fp16.h>

// QAvgPool2d: 2x2/stride-2 avg pool with fp16 (e5m10) RNE quantization at
// every accumulation step. Input fp32 (32,256,112,112), output fp32
// (32,256,56,56). Pure streaming: 411 MB read + 103 MB write, no reuse.

constexpr int B  = 32, C = 256, H = 112, W = 112;
constexpr int OH = 56, OW = 56;
constexpr int HW   = H * W;        // 12544
constexpr int OHOW = OH * OW;      // 3136
constexpr int NOUT = B * C * OH * OW;
constexpr int PW   = OW / 2;       // 28 float4-columns per input row (2 outputs each)
constexpr int RP   = OH / 2;       // 28 output-row pairs

// Native clang vectors — accepted by __builtin_nontemporal_{load,store}.
typedef float vfloat4 __attribute__((ext_vector_type(4)));
typedef float vfloat2 __attribute__((ext_vector_type(2)));

// fp16 quantize: float -> half (RNE, HW v_cvt) -> float. Matches
// float_quantize(EXP=5, MAN=10) incl. subnormals; saturation unreachable here.
__device__ __forceinline__ float q16(float v) {
    return __half2float(__float2half(v));
}

__device__ __forceinline__ float pool4(float x00, float x01, float x10, float x11) {
    float acc = q16(x00);          // reference order (0,0),(0,1),(1,0),(1,1)
    acc = q16(acc + x01);
    acc = q16(acc + x10);
    acc = q16(acc + x11);
    return q16(acc * 0.25f);
}

__global__ __launch_bounds__(256)
void qavgpool2d_kernel(const float* __restrict__ x, float* __restrict__ y) {
    int t = blockIdx.x * blockDim.x + threadIdx.x;  // 4 outputs per thread

    // Lane-stride-16B mapping: one float4 per input row, two row-pairs deep.
    int pw  = t % PW;              // which float4 within the row
    int tmp = t / PW;
    int r2  = tmp % RP;            // output row-pair index
    int bc  = tmp / RP;            // fused (b,c)

    const float* xb = x + (size_t)bc * HW + (r2 * 4) * W + pw * 4;

    // Four input rows, each one aligned float4; consecutive lanes are
    // byte-contiguous within each instruction (448 B runs, no gaps).
    vfloat4 a0 = __builtin_nontemporal_load(reinterpret_cast<const vfloat4*>(xb));
    vfloat4 a1 = __builtin_nontemporal_load(reinterpret_cast<const vfloat4*>(xb + W));
    vfloat4 a2 = __builtin_nontemporal_load(reinterpret_cast<const vfloat4*>(xb + 2 * W));
    vfloat4 a3 = __builtin_nontemporal_load(reinterpret_cast<const vfloat4*>(xb + 3 * W));

    vfloat2 o0, o1;
    o0.x = pool4(a0.x, a0.y, a1.x, a1.y);
    o0.y = pool4(a0.z, a0.w, a1.z, a1.w);
    o1.x = pool4(a2.x, a2.y, a3.x, a3.y);
    o1.y = pool4(a2.z, a2.w, a3.z, a3.w);

    float* yb = y + (size_t)bc * OHOW + (r2 * 2) * OW + pw * 2;
    __builtin_nontemporal_store(o0, reinterpret_cast<vfloat2*>(yb));
    __builtin_nontemporal_store(o1, reinterpret_cast<vfloat2*>(yb + OW));
}

extern "C" void kernel_launch(void* const* d_in, const int* in_sizes, int n_in,
                              void* d_out, int out_size, void* d_ws, size_t ws_size,
                              hipStream_t stream) {
    const float* x = (const float*)d_in[0];
    float*       y = (float*)d_out;

    constexpr int threads = 256;
    constexpr int nthreads_total = NOUT / 4;          // 6,422,528
    constexpr int blocks = nthreads_total / threads;  // 25,088 exactly

    qavgpool2d_kernel<<<blocks, threads, 0, stream>>>(x, y);
}